// Round 5
// baseline (88.019 us; speedup 1.0000x reference)
//
#include <hip/hip_runtime.h>

// Dims fixed by reference setup_inputs
#define CIN  128
#define CS   32
#define CHUNKF 32768       // HW*T floats per (n, channel)
#define PPOS 4             // hw positions per fused block

typedef __attribute__((ext_vector_type(2))) float f32x2;

// ws float layout:
// [0,4096)      qw1   [32][128]
// [4096,8192)   qw2   [128][32]
// [8192,8320)   msum  [128]
// [8448,12544)  qw1T  [128][32]   qw1T[c*32+o] = qw1[o][c]
// [12544,16640) qw2T  [32][128]   qw2T[j*128+o] = qw2[o][j]

__global__ __launch_bounds__(128) void wnorm_kernel(
    const float* __restrict__ v1, const float* __restrict__ g1,
    const float* __restrict__ v2, const float* __restrict__ g2,
    float* __restrict__ ws) {
  int b = blockIdx.x, tid = threadIdx.x;
  if (b == 0) ws[8192 + tid] = 0.f;              // zero msum (block 0 extra duty)
  bool first = (b < 32);
  int row = first ? b : b - 32;
  int len = first ? 128 : 32;
  const float* v = first ? v1 : v2;
  const float* g = first ? g1 : g2;

  double val = 0.0;
  if (tid < len) { double t = (double)v[row * len + tid]; val = t * t; }
  for (int off = 32; off >= 1; off >>= 1) val += __shfl_down(val, off);
  __shared__ double partial[2];
  if ((tid & 63) == 0) partial[tid >> 6] = val;
  __syncthreads();
  double norm = sqrt(partial[0] + partial[1]);
  if (tid < len) {
    double w = (double)g[row] * (double)v[row * len + tid] / norm;
    double qd = rint(w * 32.0) * 0.03125;        // step = 2/64, round-half-even
    qd = fmin(fmax(qd, -2.0), 1.984375);
    float qf = (float)qd;
    if (first) {                                 // row=o1, tid=c
      ws[row * 128 + tid]         = qf;          // qw1
      ws[8448 + tid * 32 + row]   = qf;          // qw1T
    } else {                                     // row=o2, tid=j
      ws[4096 + row * 32 + tid]   = qf;          // qw2
      ws[12544 + tid * 128 + row] = qf;          // qw2T
    }
  }
}

// msum[i] += sum over chunk of (T - t) * x   (scaled later by 1/(N*HW*T))
__global__ __launch_bounds__(256) void mean_kernel(
    const float* __restrict__ x, float* __restrict__ msum) {
  int b = blockIdx.x, tid = threadIdx.x;
  int chunk = b >> 2, quarter = b & 3;      // chunk = n*128 + i
  int i = chunk & 127;
  const float4* xp = (const float4*)(x + (size_t)chunk * CHUNKF + (size_t)quarter * 8192);
  float acc = 0.f;
#pragma unroll
  for (int it = 0; it < 8; ++it) {
    int f4i = tid + 256 * it;
    float4 v = xp[f4i];
    int t0 = (4 * f4i) & 31;
    acc += v.x * (float)(32 - t0) + v.y * (float)(31 - t0)
         + v.z * (float)(30 - t0) + v.w * (float)(29 - t0);
  }
  for (int off = 32; off >= 1; off >>= 1) acc += __shfl_down(acc, off);
  __shared__ float part[4];
  if ((tid & 63) == 0) part[tid >> 6] = acc;
  __syncthreads();
  if (tid == 0) atomicAdd(&msum[i], part[0] + part[1] + part[2] + part[3]);
}

// Fused: u = qw2*(qw1*x); S = cumsum_t u; a = clip(S - kappa); out = diff_t a.
// Stage-1 map: wave = hw position (wv), lane = (oG:2)(tG:4); all lanes of a wave
// read the SAME 128B x-row slice -> LDS multicast, conflict-free.
// Stage-2 map: oh = tid>>4 (8 o2 each), p2 = (tid>>2)&3, tq = tid&3 (8 t each).
__global__ __launch_bounds__(256, 4) void fused_kernel(
    const float* __restrict__ x, const float* __restrict__ ws,
    float* __restrict__ out) {
  const float* qw1g = ws;            // [32][128]
  const float* qw1T = ws + 8448;     // [c][32]
  const float* qw2T = ws + 12544;    // [j][128]
  const float* msum = ws + 8192;     // [128]

  __shared__ __align__(16) float st[2][1024];   // x stage: [c8][p4][t32]
  __shared__ __align__(16) float z1[4096];      // [j32][p4][t32]
  __shared__ float zred[288];                   // kappa partials + z[32]

  const int tid = threadIdx.x;
  const int wv  = tid >> 6;          // wave id = stage-1 position
  const int oG  = (tid >> 4) & 3;    // stage-1 o-group (8 outputs)
  const int tG  = tid & 15;          // stage-1 t-pair (t = 2tG, 2tG+1)
  const int oh  = tid >> 4;          // stage-2: o2 = oh*8..+7
  const int p2  = (tid >> 2) & 3;
  const int tq  = tid & 3;           // stage-2 t-block: t = tq*8..+7

  const int n   = blockIdx.x >> 8;
  const int hw0 = (blockIdx.x & 255) * PPOS;
  const float* xb = x + (size_t)n * CIN * CHUNKF + (size_t)hw0 * 32;

  // staging role: channel c_s, 16B slot sl
  const int c_s = tid >> 5, sl = tid & 31;
  const float* xsrc = xb + (size_t)c_s * CHUNKF + sl * 4;
  float* sdst = &st[0][0] + c_s * 128 + sl * 4;

  // issue chunk-0 x load early
  float4 xr = *(const float4*)xsrc;

  // ---- kappa phase: z[j] = (qw1 . msum)/131072 ; kap[o] = qw2T^T z
  {
    int j = tid & 31, g = tid >> 5;
    float pp = 0.f;
    const float* qr = qw1g + j * 128 + g * 16;
    const float* mr = msum + g * 16;
#pragma unroll
    for (int cc = 0; cc < 16; ++cc) pp += qr[cc] * mr[cc];
    zred[j * 8 + g] = pp;
  }
  __syncthreads();
  if (tid < 32) {
    float t = 0.f;
#pragma unroll
    for (int g = 0; g < 8; ++g) t += zred[tid * 8 + g];
    zred[256 + tid] = t * (1.0f / 131072.0f);
  }
  __syncthreads();

  float kap[8];
#pragma unroll
  for (int o = 0; o < 8; ++o) kap[o] = 0.f;
  {
    const float* w2k = qw2T + oh * 8;
#pragma unroll 4
    for (int j = 0; j < 32; ++j) {
      float zj = zred[256 + j];
      float4 wA = *(const float4*)(w2k + j * 128);
      float4 wB = *(const float4*)(w2k + j * 128 + 4);
      kap[0] += wA.x * zj; kap[1] += wA.y * zj;
      kap[2] += wA.z * zj; kap[3] += wA.w * zj;
      kap[4] += wB.x * zj; kap[5] += wB.y * zj;
      kap[6] += wB.z * zj; kap[7] += wB.w * zj;
    }
  }

  // publish chunk 0
  *(float4*)sdst = xr;
  __syncthreads();

  // ---- stage 1: acc1[k]{t-pair} = sum_c qw1T[c][oG*8+k] * x[c][wv][2tG..]
  f32x2 acc1[8];
#pragma unroll
  for (int k = 0; k < 8; ++k) acc1[k] = 0.f;

  const float* wrow = qw1T + oG * 8;               // global, L1-hot (16 KB)
  const float* srow = &st[0][0] + wv * 32 + tG * 2;

  for (int ch = 0; ch < 16; ++ch) {
    if (ch < 15) xr = *(const float4*)(xsrc + (size_t)(ch + 1) * 8 * CHUNKF);
    const float* sb = srow + (ch & 1) * 1024;
    const float* wb = wrow + ch * 8 * 32;
#pragma unroll
    for (int c = 0; c < 8; ++c) {
      f32x2 xv = *(const f32x2*)(sb + c * 128);
      float4 wA = *(const float4*)(wb + c * 32);
      float4 wB = *(const float4*)(wb + c * 32 + 4);
      acc1[0] += xv * wA.x;  acc1[1] += xv * wA.y;
      acc1[2] += xv * wA.z;  acc1[3] += xv * wA.w;
      acc1[4] += xv * wB.x;  acc1[5] += xv * wB.y;
      acc1[6] += xv * wB.z;  acc1[7] += xv * wB.w;
    }
    if (ch < 15) *(float4*)(sdst + ((ch + 1) & 1) * 1024) = xr;
    __syncthreads();
  }

  // ---- z1 writeout: z1[o1][wv][t]
#pragma unroll
  for (int k = 0; k < 8; ++k)
    *(f32x2*)(&z1[0] + (oG * 8 + k) * 128 + wv * 32 + tG * 2) = acc1[k];
  __syncthreads();

  // ---- stage 2: a2[o]{4 t-pairs} = sum_j qw2T[j][oh*8+o] * z1[j][p2][tq*8..]
  f32x2 a2[8][4];
#pragma unroll
  for (int o = 0; o < 8; ++o)
#pragma unroll
    for (int r = 0; r < 4; ++r) a2[o][r] = 0.f;

  const float* w2p = qw2T + oh * 8;
  const float* zl  = &z1[0] + p2 * 32 + tq * 8;
#pragma unroll 4
  for (int j = 0; j < 32; ++j) {
    float4 zA = *(const float4*)(zl + j * 128);
    float4 zB = *(const float4*)(zl + j * 128 + 4);
    f32x2 zp0 = {zA.x, zA.y}, zp1 = {zA.z, zA.w};
    f32x2 zp2 = {zB.x, zB.y}, zp3 = {zB.z, zB.w};
    float4 wA = *(const float4*)(w2p + j * 128);
    float4 wB = *(const float4*)(w2p + j * 128 + 4);
    float w8[8] = {wA.x, wA.y, wA.z, wA.w, wB.x, wB.y, wB.z, wB.w};
#pragma unroll
    for (int o = 0; o < 8; ++o) {
      a2[o][0] += zp0 * w8[o];
      a2[o][1] += zp1 * w8[o];
      a2[o][2] += zp2 * w8[o];
      a2[o][3] += zp3 * w8[o];
    }
  }

  // ---- epilogue: cumsum over t, -kappa, clip, diff, store
  float* outb = out + (size_t)n * CIN * CHUNKF + (size_t)(hw0 + p2) * 32 + tq * 8;
#pragma unroll
  for (int o = 0; o < 8; ++o) {
    float c0 = a2[o][0].x;
    float c1 = c0 + a2[o][0].y;
    float c2 = c1 + a2[o][1].x;
    float c3 = c2 + a2[o][1].y;
    float c4 = c3 + a2[o][2].x;
    float c5 = c4 + a2[o][2].y;
    float c6 = c5 + a2[o][3].x;
    float c7 = c6 + a2[o][3].y;
    float run = c7;
    float r1 = __shfl_up(run, 1); if (tq >= 1) run += r1;
    float r2 = __shfl_up(run, 2); if (tq >= 2) run += r2;
    float base = (run - c7) - kap[o];         // S[t0-1] - kappa
    float prev = (tq == 0) ? 0.f : fminf(fmaxf(base, -6.f), 6.f);
    float A0 = fminf(fmaxf(base + c0, -6.f), 6.f);
    float A1 = fminf(fmaxf(base + c1, -6.f), 6.f);
    float A2 = fminf(fmaxf(base + c2, -6.f), 6.f);
    float A3 = fminf(fmaxf(base + c3, -6.f), 6.f);
    float A4 = fminf(fmaxf(base + c4, -6.f), 6.f);
    float A5 = fminf(fmaxf(base + c5, -6.f), 6.f);
    float A6 = fminf(fmaxf(base + c6, -6.f), 6.f);
    float A7 = fminf(fmaxf(base + c7, -6.f), 6.f);
    float* op = outb + (size_t)(oh * 8 + o) * CHUNKF;
    ((float4*)op)[0] = make_float4(A0 - prev, A1 - A0, A2 - A1, A3 - A2);
    ((float4*)op)[1] = make_float4(A4 - A3, A5 - A4, A6 - A5, A7 - A6);
  }
}

extern "C" void kernel_launch(void* const* d_in, const int* in_sizes, int n_in,
                              void* d_out, int out_size, void* d_ws, size_t ws_size,
                              hipStream_t stream) {
  const float* x  = (const float*)d_in[0];
  const float* v1 = (const float*)d_in[1];
  const float* g1 = (const float*)d_in[2];
  const float* v2 = (const float*)d_in[3];
  const float* g2 = (const float*)d_in[4];
  float* ws  = (float*)d_ws;
  float* out = (float*)d_out;

  wnorm_kernel<<<160, 128, 0, stream>>>(v1, g1, v2, g2, ws);
  mean_kernel<<<2048, 256, 0, stream>>>(x, ws + 8192);
  fused_kernel<<<1024, 256, 0, stream>>>(x, ws, out);
}

// Round 6
// 68.963 us; speedup vs baseline: 1.2763x; 1.2763x over previous
//
#include <hip/hip_runtime.h>

// Dims fixed by reference setup_inputs
#define CIN  128
#define CS   32
#define CHUNKF 32768       // HW*T floats per (n, channel)

typedef __attribute__((ext_vector_type(2))) float f32x2;

// ws float layout:
// [0,4096)      qw1   [32][128]
// [4096,8192)   qw2   [128][32]
// [8192,8320)   msum  [128]
// [8320,8448)   kappa [128]
// [8448,12544)  qw1T  [128][32]   qw1T[c*32+o] = qw1[o][c]
// [12544,16640) qw2T  [32][128]   qw2T[j*128+o] = qw2[o][j]

__global__ __launch_bounds__(128) void wnorm_kernel(
    const float* __restrict__ v1, const float* __restrict__ g1,
    const float* __restrict__ v2, const float* __restrict__ g2,
    float* __restrict__ ws) {
  int b = blockIdx.x, tid = threadIdx.x;
  if (b == 0) ws[8192 + tid] = 0.f;              // zero msum
  bool first = (b < 32);
  int row = first ? b : b - 32;
  int len = first ? 128 : 32;
  const float* v = first ? v1 : v2;
  const float* g = first ? g1 : g2;

  double val = 0.0;
  if (tid < len) { double t = (double)v[row * len + tid]; val = t * t; }
  for (int off = 32; off >= 1; off >>= 1) val += __shfl_down(val, off);
  __shared__ double partial[2];
  if ((tid & 63) == 0) partial[tid >> 6] = val;
  __syncthreads();
  double norm = sqrt(partial[0] + partial[1]);
  if (tid < len) {
    double w = (double)g[row] * (double)v[row * len + tid] / norm;
    double qd = rint(w * 32.0) * 0.03125;        // step = 2/64, round-half-even
    qd = fmin(fmax(qd, -2.0), 1.984375);
    float qf = (float)qd;
    if (first) {                                 // row=o1, tid=c
      ws[row * 128 + tid]         = qf;          // qw1
      ws[8448 + tid * 32 + row]   = qf;          // qw1T
    } else {                                     // row=o2, tid=j
      ws[4096 + row * 32 + tid]   = qf;          // qw2
      ws[12544 + tid * 128 + row] = qf;          // qw2T
    }
  }
}

// msum[i] += sum over chunk of (T - t) * x   (scaled later by 1/(N*HW*T))
__global__ __launch_bounds__(256) void mean_kernel(
    const float* __restrict__ x, float* __restrict__ msum) {
  int b = blockIdx.x, tid = threadIdx.x;
  int chunk = b >> 2, quarter = b & 3;      // chunk = n*128 + i
  int i = chunk & 127;
  const float4* xp = (const float4*)(x + (size_t)chunk * CHUNKF + (size_t)quarter * 8192);
  float acc = 0.f;
#pragma unroll
  for (int it = 0; it < 8; ++it) {
    int f4i = tid + 256 * it;
    float4 v = xp[f4i];
    int t0 = (4 * f4i) & 31;
    acc += v.x * (float)(32 - t0) + v.y * (float)(31 - t0)
         + v.z * (float)(30 - t0) + v.w * (float)(29 - t0);
  }
  for (int off = 32; off >= 1; off >>= 1) acc += __shfl_down(acc, off);
  __shared__ float part[4];
  if ((tid & 63) == 0) part[tid >> 6] = acc;
  __syncthreads();
  if (tid == 0) atomicAdd(&msum[i], part[0] + part[1] + part[2] + part[3]);
}

// kappa[o2] = sum_j qw2[o2][j] * (sum_c qw1[j][c] * mbar[c])
__global__ __launch_bounds__(128) void kappa_kernel(float* __restrict__ ws) {
  __shared__ float z[32];
  int tid = threadIdx.x;
  const float* qw1 = ws;
  const float* qw2 = ws + 4096;
  const float* msum = ws + 8192;
  if (tid < 32) {
    float acc = 0.f;
    for (int c = 0; c < 128; ++c) acc += qw1[tid * 128 + c] * msum[c];
    z[tid] = acc * (1.0f / 131072.0f);
  }
  __syncthreads();
  float k = 0.f;
  for (int j = 0; j < 32; ++j) k += qw2[tid * 32 + j] * z[j];
  ws[8320 + tid] = k;
}

// Fused: u = qw2*(qw1*x); S = cumsum_t u; a = clip(S - kappa); out = diff_t a.
// WAVE-PRIVATE design: wave wv owns position pos = blockIdx.x*4+wv entirely.
// Lane = (oq:8)(u:8); stage 1: o1 = oq*4..+3, t = 4u..4u+3, x straight from
// global (L3-hot, 8-deep register prefetch), weights via LDS broadcast.
// z1 in a wave-private LDS slab (no __syncthreads needed — wave-synchronous).
// Stage 2: o2 = oq*16..+15, same t. One barrier total (w1 preload).
__global__ __launch_bounds__(256, 4) void fused_kernel(
    const float* __restrict__ x, const float* __restrict__ ws,
    float* __restrict__ out) {
  const float* qw1T = ws + 8448;     // [c][32]
  const float* qw2T = ws + 12544;    // [j][128]
  const float* kap  = ws + 8320;     // [128]

  __shared__ __align__(16) float w1s[4096];   // 16 KB qw1T copy
  __shared__ __align__(16) float zw[4096];    // 4 KB/wave: z[o1=32][t=32]

  const int tid = threadIdx.x;
  const int wv  = tid >> 6;          // wave -> position
  const int oq  = (tid >> 3) & 7;    // lane/8
  const int u   = tid & 7;           // t-quad: t = 4u..4u+3

  const int pos = blockIdx.x * 4 + wv;
  const int n   = pos >> 10, hw = pos & 1023;
  const float* xpos = x + (size_t)n * CIN * CHUNKF + (size_t)hw * 32 + u * 4;

  // issue first 8 x loads before the weight preload (hide L3 latency)
  float4 xn[8];
#pragma unroll
  for (int k = 0; k < 8; ++k) xn[k] = *(const float4*)(xpos + (size_t)k * CHUNKF);

#pragma unroll
  for (int k = 0; k < 16; ++k) w1s[k * 256 + tid] = qw1T[k * 256 + tid];
  __syncthreads();

  // ---- stage 1: acc1[o]{2 t-pairs} = sum_c qw1T[c][oq*4+o] * x[c][pos][t]
  f32x2 acc1[4][2];
#pragma unroll
  for (int o = 0; o < 4; ++o) { acc1[o][0] = 0.f; acc1[o][1] = 0.f; }

  for (int ch = 0; ch < 16; ++ch) {
#pragma unroll
    for (int cc = 0; cc < 8; ++cc) {
      const int c = ch * 8 + cc;
      float4 xv = xn[cc];
      if (ch < 15) xn[cc] = *(const float4*)(xpos + (size_t)(c + 8) * CHUNKF);
      float4 wv4 = *(const float4*)&w1s[c * 32 + oq * 4];
      f32x2 xp0 = {xv.x, xv.y}, xp1 = {xv.z, xv.w};
      acc1[0][0] += xp0 * wv4.x;  acc1[0][1] += xp1 * wv4.x;
      acc1[1][0] += xp0 * wv4.y;  acc1[1][1] += xp1 * wv4.y;
      acc1[2][0] += xp0 * wv4.z;  acc1[2][1] += xp1 * wv4.z;
      acc1[3][0] += xp0 * wv4.w;  acc1[3][1] += xp1 * wv4.w;
    }
  }

  // ---- z to wave-private LDS: zw[wv][o1][t]
  float* zb = &zw[0] + wv * 1024;
#pragma unroll
  for (int o = 0; o < 4; ++o) {
    float4 zv = make_float4(acc1[o][0].x, acc1[o][0].y,
                            acc1[o][1].x, acc1[o][1].y);
    *(float4*)(zb + (oq * 4 + o) * 32 + u * 4) = zv;
  }

  // ---- stage 2: a2[o]{2 t-pairs} = sum_j qw2T[j][oq*16+o] * z[j][t]
  f32x2 a2[16][2];
#pragma unroll
  for (int o = 0; o < 16; ++o) { a2[o][0] = 0.f; a2[o][1] = 0.f; }

  const float* w2p = qw2T + oq * 16;
#pragma unroll 4
  for (int j = 0; j < 32; ++j) {
    float4 zv = *(const float4*)(zb + j * 32 + u * 4);
    f32x2 zp0 = {zv.x, zv.y}, zp1 = {zv.z, zv.w};
    float4 wA = *(const float4*)(w2p + j * 128);
    float4 wB = *(const float4*)(w2p + j * 128 + 4);
    float4 wC = *(const float4*)(w2p + j * 128 + 8);
    float4 wD = *(const float4*)(w2p + j * 128 + 12);
    float w16[16] = {wA.x, wA.y, wA.z, wA.w, wB.x, wB.y, wB.z, wB.w,
                     wC.x, wC.y, wC.z, wC.w, wD.x, wD.y, wD.z, wD.w};
#pragma unroll
    for (int o = 0; o < 16; ++o) {
      a2[o][0] += zp0 * w16[o];
      a2[o][1] += zp1 * w16[o];
    }
  }

  // ---- epilogue: cumsum over t, -kappa, clip, diff, store
  float4 kA = *(const float4*)(kap + oq * 16);
  float4 kB = *(const float4*)(kap + oq * 16 + 4);
  float4 kC = *(const float4*)(kap + oq * 16 + 8);
  float4 kD = *(const float4*)(kap + oq * 16 + 12);
  float kv[16] = {kA.x, kA.y, kA.z, kA.w, kB.x, kB.y, kB.z, kB.w,
                  kC.x, kC.y, kC.z, kC.w, kD.x, kD.y, kD.z, kD.w};
  float* outb = out + (size_t)n * CIN * CHUNKF + (size_t)hw * 32 + u * 4;

#pragma unroll
  for (int o = 0; o < 16; ++o) {
    float c0 = a2[o][0].x;
    float c1 = c0 + a2[o][0].y;
    float c2 = c1 + a2[o][1].x;
    float c3 = c2 + a2[o][1].y;
    float run = c3;                  // 8-lane (u) inclusive prefix of quad sums
    float r1 = __shfl_up(run, 1); if (u >= 1) run += r1;
    float r2 = __shfl_up(run, 2); if (u >= 2) run += r2;
    float r4 = __shfl_up(run, 4); if (u >= 4) run += r4;
    float base = (run - c3) - kv[o];          // S[4u-1] - kappa
    float prev = (u == 0) ? 0.f : fminf(fmaxf(base, -6.f), 6.f);
    float A0 = fminf(fmaxf(base + c0, -6.f), 6.f);
    float A1 = fminf(fmaxf(base + c1, -6.f), 6.f);
    float A2 = fminf(fmaxf(base + c2, -6.f), 6.f);
    float A3 = fminf(fmaxf(base + c3, -6.f), 6.f);
    float* op = outb + (size_t)(oq * 16 + o) * CHUNKF;
    *(float4*)op = make_float4(A0 - prev, A1 - A0, A2 - A1, A3 - A2);
  }
}

extern "C" void kernel_launch(void* const* d_in, const int* in_sizes, int n_in,
                              void* d_out, int out_size, void* d_ws, size_t ws_size,
                              hipStream_t stream) {
  const float* x  = (const float*)d_in[0];
  const float* v1 = (const float*)d_in[1];
  const float* g1 = (const float*)d_in[2];
  const float* v2 = (const float*)d_in[3];
  const float* g2 = (const float*)d_in[4];
  float* ws  = (float*)d_ws;
  float* out = (float*)d_out;

  wnorm_kernel<<<160, 128, 0, stream>>>(v1, g1, v2, g2, ws);
  mean_kernel<<<2048, 256, 0, stream>>>(x, ws + 8192);
  kappa_kernel<<<1, 128, 0, stream>>>(ws);
  fused_kernel<<<1024, 256, 0, stream>>>(x, ws, out);
}

// Round 7
// 63.597 us; speedup vs baseline: 1.3840x; 1.0844x over previous
//
#include <hip/hip_runtime.h>

// Dims fixed by reference setup_inputs
#define CIN  128
#define CS   32
#define CHUNKF 32768       // HW*T floats per (n, channel)

typedef __attribute__((ext_vector_type(2))) float f32x2;

// ws float layout:
// [0,4096)      qw1   [32][128]
// [4096,8192)   qw2   [128][32]
// [8192,8320)   msum  [128]
// [8320,8448)   kappa [128]
// [8448,12544)  qw1T  [128][32]   qw1T[c*32+o] = qw1[o][c]
// [12544,16640) qw2T  [32][128]   qw2T[j*128+o] = qw2[o][j]

// blocks [0,2048): mean partial sums; blocks [2048,2208): weight-norm rows.
__global__ __launch_bounds__(256) void wnorm_mean_kernel(
    const float* __restrict__ x,
    const float* __restrict__ v1, const float* __restrict__ g1,
    const float* __restrict__ v2, const float* __restrict__ g2,
    float* __restrict__ ws) {
  int tid = threadIdx.x;
  if (blockIdx.x < 2048) {
    // ---- mean duty: msum[i] += sum over quarter-chunk of (T - t) * x
    int b = blockIdx.x;
    int chunk = b >> 2, quarter = b & 3;      // chunk = n*128 + i
    int i = chunk & 127;
    const float4* xp = (const float4*)(x + (size_t)chunk * CHUNKF + (size_t)quarter * 8192);
    float acc = 0.f;
#pragma unroll
    for (int it = 0; it < 8; ++it) {
      int f4i = tid + 256 * it;
      float4 v = xp[f4i];
      int t0 = (4 * f4i) & 31;
      acc += v.x * (float)(32 - t0) + v.y * (float)(31 - t0)
           + v.z * (float)(30 - t0) + v.w * (float)(29 - t0);
    }
    for (int off = 32; off >= 1; off >>= 1) acc += __shfl_down(acc, off);
    __shared__ float part[4];
    if ((tid & 63) == 0) part[tid >> 6] = acc;
    __syncthreads();
    if (tid == 0) atomicAdd(&ws[8192 + i], part[0] + part[1] + part[2] + part[3]);
  } else {
    // ---- weight-norm duty
    int b = blockIdx.x - 2048;
    bool first = (b < 32);
    int row = first ? b : b - 32;
    int len = first ? 128 : 32;
    const float* v = first ? v1 : v2;
    const float* g = first ? g1 : g2;

    double val = 0.0;
    if (tid < len) { double t = (double)v[row * len + tid]; val = t * t; }
    for (int off = 32; off >= 1; off >>= 1) val += __shfl_down(val, off);
    __shared__ double partial[4];
    if ((tid & 63) == 0) partial[tid >> 6] = val;
    __syncthreads();
    double norm = sqrt(partial[0] + partial[1]);   // len <= 128 -> waves 0,1
    if (tid < len) {
      double w = (double)g[row] * (double)v[row * len + tid] / norm;
      double qd = rint(w * 32.0) * 0.03125;        // step = 2/64, round-half-even
      qd = fmin(fmax(qd, -2.0), 1.984375);
      float qf = (float)qd;
      if (first) {                                 // row=o1, tid=c
        ws[row * 128 + tid]         = qf;          // qw1
        ws[8448 + tid * 32 + row]   = qf;          // qw1T
      } else {                                     // row=o2, tid=j
        ws[4096 + row * 32 + tid]   = qf;          // qw2
        ws[12544 + tid * 128 + row] = qf;          // qw2T
      }
    }
  }
}

// kappa[o2] = sum_j qw2[o2][j] * (sum_c qw1[j][c] * mbar[c])
__global__ __launch_bounds__(128) void kappa_kernel(float* __restrict__ ws) {
  __shared__ float z[32];
  int tid = threadIdx.x;
  const float* qw1 = ws;
  const float* qw2 = ws + 4096;
  const float* msum = ws + 8192;
  if (tid < 32) {
    float acc = 0.f;
    for (int c = 0; c < 128; ++c) acc += qw1[tid * 128 + c] * msum[c];
    z[tid] = acc * (1.0f / 131072.0f);
  }
  __syncthreads();
  float k = 0.f;
  for (int j = 0; j < 32; ++j) k += qw2[tid * 32 + j] * z[j];
  ws[8320 + tid] = k;
}

// Fused: u = qw2*(qw1*x); S = cumsum_t u; a = clip(S - kappa); out = diff_t a.
// Block = 4 waves, wave wv owns position hw0+wv. Lane = (oq:3)(u:3).
// Stage 1: o1 = oq*4..+3, t = 4u..4u+3; x double-buffer-staged in LDS
// (barrier -> issue prefetch -> compute(cover) -> LDS write), w1 bf16 in LDS.
// Stage 2: z handoff via ds_bpermute (wave-synchronous, NO barriers);
// o2 = oq*16..+15; w2 f32 in LDS. Epilogue as round 6 (proven).
__global__ __launch_bounds__(256, 4) void fused_kernel(
    const float* __restrict__ x, const float* __restrict__ ws,
    float* __restrict__ out) {
  const float* qw1T = ws + 8448;     // [c][32]
  const float* qw2T = ws + 12544;    // [j][128]
  const float* kap  = ws + 8320;     // [128]

  __shared__ __align__(16) float st[2][1024];        //  8 KB x stage [buf][c8][p4][t32]
  __shared__ __align__(8)  unsigned short w1h[4096]; //  8 KB qw1T bf16 [c][o1]
  __shared__ __align__(16) float w2s[4096];          // 16 KB qw2T f32 [j][o2]

  const int tid  = threadIdx.x;
  const int wv   = tid >> 6;
  const int lane = tid & 63;
  const int oq   = lane >> 3;        // 0..7
  const int u    = lane & 7;         // t-quad: t = 4u..4u+3

  const int n   = blockIdx.x >> 8;
  const int hw0 = (blockIdx.x & 255) * 4;
  const int hw  = hw0 + wv;

  // staging role: channel c_s = tid>>5, slot r = tid&31 (p = r>>3, tq = r&7)
  const int r = tid & 31;
  const float* xsrc = x + (size_t)n * CIN * CHUNKF + (size_t)(tid >> 5) * CHUNKF
                      + (size_t)(hw0 + (r >> 3)) * 32 + (r & 7) * 4;
  float* sdst = &st[0][0] + tid * 4;

  // chunk-0 load issued first (covered by weight preload below)
  float4 xr = *(const float4*)xsrc;

  // weight preload
#pragma unroll
  for (int k = 0; k < 16; ++k) {
    float f = qw1T[k * 256 + tid];
    w1h[k * 256 + tid] = (unsigned short)(__float_as_uint(f) >> 16);
  }
#pragma unroll
  for (int k = 0; k < 16; ++k) w2s[k * 256 + tid] = qw2T[k * 256 + tid];

  *(float4*)sdst = xr;               // stage chunk 0 into buf 0

  f32x2 acc1[4][2];
#pragma unroll
  for (int o = 0; o < 4; ++o) { acc1[o][0] = 0.f; acc1[o][1] = 0.f; }

  const int srd = wv * 32 + u * 4;   // read offset within a buffer row-block

  // ---- stage 1: acc1[o]{2 pairs} = sum_c qw1[c][oq*4+o] * x[c][hw][4u..]
  for (int ch = 0; ch < 16; ++ch) {
    __syncthreads();                 // buf[ch&1] fully staged (vmcnt drain is free here)
    float4 xn;
    if (ch < 15) xn = *(const float4*)(xsrc + (size_t)(ch + 1) * 8 * CHUNKF);
    const float* sb = &st[ch & 1][0] + srd;
    const unsigned short* wb = w1h + (ch * 8) * 32 + oq * 4;
#pragma unroll
    for (int cl = 0; cl < 8; ++cl) {
      float4 sv = *(const float4*)(sb + cl * 128);
      ushort4 wq = *(const ushort4*)(wb + cl * 32);
      float w0 = __uint_as_float((unsigned)wq.x << 16);
      float w1 = __uint_as_float((unsigned)wq.y << 16);
      float w2 = __uint_as_float((unsigned)wq.z << 16);
      float w3 = __uint_as_float((unsigned)wq.w << 16);
      f32x2 xp0 = {sv.x, sv.y}, xp1 = {sv.z, sv.w};
      acc1[0][0] += xp0 * w0;  acc1[0][1] += xp1 * w0;
      acc1[1][0] += xp0 * w1;  acc1[1][1] += xp1 * w1;
      acc1[2][0] += xp0 * w2;  acc1[2][1] += xp1 * w2;
      acc1[3][0] += xp0 * w3;  acc1[3][1] += xp1 * w3;
    }
    if (ch < 15) *(float4*)(sdst + ((ch + 1) & 1) * 1024) = xn;  // write late
  }
  // no barrier: stage 2 + epilogue are wave-local (bpermute) + read-only w2s

  // ---- stage 2: a2[o]{2 pairs} = sum_j qw2T[j][oq*16+o] * z[j][4u..]
  // z[j][quad u] lives in lane (j>>2)*8+u, regs acc1[j&3][0..1]
  f32x2 a2[16][2];
#pragma unroll
  for (int o = 0; o < 16; ++o) { a2[o][0] = 0.f; a2[o][1] = 0.f; }

  const int baddr = u * 4;           // bpermute byte addr base (srcLane*4)
  const float* w2p = w2s + oq * 16;
#pragma unroll
  for (int j = 0; j < 32; ++j) {
    int zw0 = __builtin_amdgcn_ds_bpermute(baddr + (j >> 2) * 32,
                                           __float_as_int(acc1[j & 3][0][0]));
    int zw1 = __builtin_amdgcn_ds_bpermute(baddr + (j >> 2) * 32,
                                           __float_as_int(acc1[j & 3][0][1]));
    int zw2 = __builtin_amdgcn_ds_bpermute(baddr + (j >> 2) * 32,
                                           __float_as_int(acc1[j & 3][1][0]));
    int zw3 = __builtin_amdgcn_ds_bpermute(baddr + (j >> 2) * 32,
                                           __float_as_int(acc1[j & 3][1][1]));
    f32x2 zp0 = {__int_as_float(zw0), __int_as_float(zw1)};
    f32x2 zp1 = {__int_as_float(zw2), __int_as_float(zw3)};
    float4 wA = *(const float4*)(w2p + j * 128);
    float4 wB = *(const float4*)(w2p + j * 128 + 4);
    float4 wC = *(const float4*)(w2p + j * 128 + 8);
    float4 wD = *(const float4*)(w2p + j * 128 + 12);
    float w16[16] = {wA.x, wA.y, wA.z, wA.w, wB.x, wB.y, wB.z, wB.w,
                     wC.x, wC.y, wC.z, wC.w, wD.x, wD.y, wD.z, wD.w};
#pragma unroll
    for (int o = 0; o < 16; ++o) {
      a2[o][0] += zp0 * w16[o];
      a2[o][1] += zp1 * w16[o];
    }
  }

  // ---- epilogue: cumsum over t, -kappa, clip, diff, store (round-6 proven)
  float4 kA = *(const float4*)(kap + oq * 16);
  float4 kB = *(const float4*)(kap + oq * 16 + 4);
  float4 kC = *(const float4*)(kap + oq * 16 + 8);
  float4 kD = *(const float4*)(kap + oq * 16 + 12);
  float kv[16] = {kA.x, kA.y, kA.z, kA.w, kB.x, kB.y, kB.z, kB.w,
                  kC.x, kC.y, kC.z, kC.w, kD.x, kD.y, kD.z, kD.w};
  float* outb = out + (size_t)n * CIN * CHUNKF + (size_t)hw * 32 + u * 4;

#pragma unroll
  for (int o = 0; o < 16; ++o) {
    float c0 = a2[o][0][0];
    float c1 = c0 + a2[o][0][1];
    float c2 = c1 + a2[o][1][0];
    float c3 = c2 + a2[o][1][1];
    float run = c3;                  // 8-lane (u) inclusive prefix of quad sums
    float r1 = __shfl_up(run, 1); if (u >= 1) run += r1;
    float r2 = __shfl_up(run, 2); if (u >= 2) run += r2;
    float r4 = __shfl_up(run, 4); if (u >= 4) run += r4;
    float base = (run - c3) - kv[o];          // S[4u-1] - kappa
    float prev = (u == 0) ? 0.f : fminf(fmaxf(base, -6.f), 6.f);
    float A0 = fminf(fmaxf(base + c0, -6.f), 6.f);
    float A1 = fminf(fmaxf(base + c1, -6.f), 6.f);
    float A2 = fminf(fmaxf(base + c2, -6.f), 6.f);
    float A3 = fminf(fmaxf(base + c3, -6.f), 6.f);
    float* op = outb + (size_t)(oq * 16 + o) * CHUNKF;
    *(float4*)op = make_float4(A0 - prev, A1 - A0, A2 - A1, A3 - A2);
  }
}

extern "C" void kernel_launch(void* const* d_in, const int* in_sizes, int n_in,
                              void* d_out, int out_size, void* d_ws, size_t ws_size,
                              hipStream_t stream) {
  const float* x  = (const float*)d_in[0];
  const float* v1 = (const float*)d_in[1];
  const float* g1 = (const float*)d_in[2];
  const float* v2 = (const float*)d_in[3];
  const float* g2 = (const float*)d_in[4];
  float* ws  = (float*)d_ws;
  float* out = (float*)d_out;

  hipMemsetAsync(ws + 8192, 0, 128 * sizeof(float), stream);
  wnorm_mean_kernel<<<2208, 256, 0, stream>>>(x, v1, g1, v2, g2, ws);
  kappa_kernel<<<1, 128, 0, stream>>>(ws);
  fused_kernel<<<1024, 256, 0, stream>>>(x, ws, out);
}